// Round 1
// 231.494 us; speedup vs baseline: 1.0432x; 1.0432x over previous
//
#include <hip/hip_runtime.h>
#include <hip/hip_bf16.h>
#include <stdint.h>

typedef __bf16 bf16x8 __attribute__((ext_vector_type(8)));
typedef float  f32x4  __attribute__((ext_vector_type(4)));

#define W1_ROWS 64
#define W1_K    128
#define W1_PAD  136   // 128 + 8 bf16 pad -> 272B row stride: ds_read_b128 spreads uniformly over banks

// Convert 8 consecutive fp32 (two float4s) to a bf16x8 MFMA fragment (RNE).
static __device__ inline bf16x8 cvt8(const float4 a, const float4 b) {
    bf16x8 r;
    r[0] = (__bf16)a.x; r[1] = (__bf16)a.y; r[2] = (__bf16)a.z; r[3] = (__bf16)a.w;
    r[4] = (__bf16)b.x; r[5] = (__bf16)b.y; r[6] = (__bf16)b.z; r[7] = (__bf16)b.w;
    return r;
}

// One group = 16 edges, gathered as 8 float4 per lane (lane quad covers 1/4 of
// the 2x256B concat row). Stage buffer = the in-flight load destinations.
struct Stage { float4 x0, x1, x2, x3, x4, x5, x6, x7; };

static __device__ inline void issue_gather(Stage& S,
                                           const float* __restrict__ zu,
                                           const float* __restrict__ zb,
                                           int r, int c, int quad) {
    const float4* up = (const float4*)(zu + (size_t)r * 64);
    const float4* vp = (const float4*)(zb + (size_t)c * 64);
    const int q2 = quad * 2;
    S.x0 = up[q2];     S.x1 = up[q2 + 1];      // k in [0,32)
    S.x2 = up[q2 + 8]; S.x3 = up[q2 + 9];      // k in [32,64)
    S.x4 = vp[q2];     S.x5 = vp[q2 + 1];      // k in [64,96)
    S.x6 = vp[q2 + 8]; S.x7 = vp[q2 + 9];      // k in [96,128)
}

// MFMA 16x16x32 bf16 layouts (measured, cdna_hip_programming.md §3):
//   A: lane holds A[m=lane&15][k=quad*8+j]
//   B: lane holds B[k=quad*8+j][n=lane&15]
//   C/D: lane reg r holds D[row=quad*4+r][col=lane&15]
__global__ __launch_bounds__(256, 4)
void edge_decoder_mfma(const float* __restrict__ zu,
                       const float* __restrict__ zb,
                       const int*   __restrict__ eidx,
                       const float* __restrict__ w1,
                       const float* __restrict__ b1,
                       const float* __restrict__ w2,
                       const float* __restrict__ b2,
                       float*       __restrict__ out,
                       const int nedges)
{
    // W1^T in LDS as bf16, row n (0..63) = W1 row n, k-contiguous, padded stride.
    __shared__ __bf16 w1s[W1_ROWS * W1_PAD];   // 17408 B

    const int lane = threadIdx.x & 63;
    const int m    = lane & 15;
    const int quad = lane >> 4;

    // ---- one-time W1 fp32->bf16 fill (64 rows x 16 chunks of 8) ----
    for (int i = threadIdx.x; i < W1_ROWS * (W1_K / 8); i += blockDim.x) {
        const int n = i >> 4, c8 = i & 15;
        const float4* wr = (const float4*)(w1 + (size_t)n * W1_K + c8 * 8);
        *(bf16x8*)(&w1s[n * W1_PAD + c8 * 8]) = cvt8(wr[0], wr[1]);
    }
    __syncthreads();

    float w2v[4], b1v[4];
#pragma unroll
    for (int t = 0; t < 4; ++t) {
        w2v[t] = w2[t * 16 + m];     // W2 column for n = t*16+m (fp32, exact)
        b1v[t] = b1[t * 16 + m];
    }
    const float b2f = b2[0];

    const int* __restrict__ rowp = eidx;
    const int* __restrict__ colp = eidx + nedges;
    const int ngroups = (nedges + 15) >> 4;

    const int wavesPerBlock = blockDim.x >> 6;
    const int gwave = blockIdx.x * wavesPerBlock + (threadIdx.x >> 6);
    const int nw    = gridDim.x * wavesPerBlock;
    const int nw2   = nw << 1;

    // Per-lane LDS base: frag(t,s) = lbase + t*16*272 + s*64  (ds offset imm)
    const char* lbase = (const char*)w1s + m * (W1_PAD * 2) + quad * 16;

    // Always-safe index load (clamped), so tail/overrun groups gather row 0.
    auto load_idx = [&](int gg, int& r, int& c) {
        int e = (gg < ngroups) ? ((gg << 4) + m) : 0;
        if (e >= nedges) e = nedges - 1;
        r = rowp[e]; c = colp[e];
    };

    auto compute_store = [&](const Stage& S, int gg) {
        bf16x8 A[4];
        A[0] = cvt8(S.x0, S.x1); A[1] = cvt8(S.x2, S.x3);
        A[2] = cvt8(S.x4, S.x5); A[3] = cvt8(S.x6, S.x7);

        f32x4 acc[4];
#pragma unroll
        for (int t = 0; t < 4; ++t)
            acc[t] = (f32x4){b1v[t], b1v[t], b1v[t], b1v[t]};   // fold b1 into init

        // s-outer: the 4 consecutive MFMAs (t=0..3) are independent chains.
#pragma unroll
        for (int s = 0; s < 4; ++s) {
#pragma unroll
            for (int t = 0; t < 4; ++t) {
                const bf16x8 bf = *(const bf16x8*)(lbase + t * (16 * W1_PAD * 2) + s * 64);
                acc[t] = __builtin_amdgcn_mfma_f32_16x16x32_bf16(A[s], bf, acc[t], 0, 0, 0);
            }
        }

        // Epilogue: h=relu(acc); lane-partial dot with W2; reduce over 16 n-lanes.
        float p[4] = {0.f, 0.f, 0.f, 0.f};
#pragma unroll
        for (int t = 0; t < 4; ++t)
#pragma unroll
            for (int rr = 0; rr < 4; ++rr)
                p[rr] = fmaf(fmaxf(acc[t][rr], 0.f), w2v[t], p[rr]);

#pragma unroll
        for (int off = 8; off >= 1; off >>= 1)
#pragma unroll
            for (int rr = 0; rr < 4; ++rr)
                p[rr] += __shfl_xor(p[rr], off, 64);

        if (m == 0) {
            const int eo = (gg << 4) + quad * 4;   // >= nedges for overrun groups -> no store
            if (eo + 3 < nedges) {
                float4 o;
                o.x = p[0] + b2f; o.y = p[1] + b2f;
                o.z = p[2] + b2f; o.w = p[3] + b2f;
                *(float4*)(out + eo) = o;
            } else {
#pragma unroll
                for (int rr = 0; rr < 4; ++rr)
                    if (eo + rr < nedges) out[eo + rr] = p[rr] + b2f;
            }
        }
    };

    // ---- 2-deep software pipeline ----
    // S0 carries groups g, g+2nw, g+4nw...; S1 carries g+nw, g+3nw, ...
    // Indices are loaded a full iteration (2 group-computes) ahead of their use.
    int g = gwave;
    int r0, c0, r1, c1;
    Stage S0, S1;

    load_idx(g,      r0, c0);
    load_idx(g + nw, r1, c1);
    issue_gather(S0, zu, zb, r0, c0, quad);
    issue_gather(S1, zu, zb, r1, c1, quad);
    load_idx(g + nw2,      r0, c0);   // pending refill target for S0
    load_idx(g + nw2 + nw, r1, c1);   // pending refill target for S1

    for (; g < ngroups; g += nw2) {
        // group g (S0): compute while S1's gathers are in flight
        compute_store(S0, g);
        issue_gather(S0, zu, zb, r0, c0, quad);        // group g+2nw
        load_idx(g + nw2 + nw2, r0, c0);               // group g+4nw pending

        // group g+nw (S1): compute while S0's refill is in flight
        compute_store(S1, g + nw);                     // overrun-safe (store self-guarded)
        issue_gather(S1, zu, zb, r1, c1, quad);        // group g+3nw
        load_idx(g + nw2 + nw2 + nw, r1, c1);          // group g+5nw pending
    }
}

extern "C" void kernel_launch(void* const* d_in, const int* in_sizes, int n_in,
                              void* d_out, int out_size, void* d_ws, size_t ws_size,
                              hipStream_t stream) {
    const float* zu = (const float*)d_in[0];
    const float* zb = (const float*)d_in[1];
    const int*   ei = (const int*)d_in[2];
    const float* w1 = (const float*)d_in[3];
    const float* b1 = (const float*)d_in[4];
    const float* w2 = (const float*)d_in[5];
    const float* b2 = (const float*)d_in[6];
    float* out = (float*)d_out;

    const int nedges = in_sizes[2] / 2;   // edge_label_index is [2, E]

    // 2048 blocks x 256 threads = 8192 waves; 4 blocks/CU resident
    // (VGPR<=128 via launch_bounds; LDS 4 x 17.4KB = 70KB/CU).
    dim3 grid(2048), block(256);
    hipLaunchKernelGGL(edge_decoder_mfma, grid, block, 0, stream,
                       zu, zb, ei, w1, b1, w2, b2, out, nedges);
}

// Round 2
// 195.253 us; speedup vs baseline: 1.2368x; 1.1856x over previous
//
#include <hip/hip_runtime.h>
#include <hip/hip_bf16.h>
#include <stdint.h>

typedef __bf16 bf16x8 __attribute__((ext_vector_type(8)));
typedef float  f32x4  __attribute__((ext_vector_type(4)));

// Convert 8 consecutive fp32 (two float4s) to a bf16x8 fragment (RNE).
static __device__ inline bf16x8 cvt8(const float4 a, const float4 b) {
    bf16x8 r;
    r[0] = (__bf16)a.x; r[1] = (__bf16)a.y; r[2] = (__bf16)a.z; r[3] = (__bf16)a.w;
    r[4] = (__bf16)b.x; r[5] = (__bf16)b.y; r[6] = (__bf16)b.z; r[7] = (__bf16)b.w;
    return r;
}

// VALU-pipe 16-lane-row reduce step: x += rotate_row(x, CTRL).
// row_ror:8/4/2/1 = 0x128/0x124/0x122/0x121 (DPP16, bound_ctrl on).
template<int CTRL>
static __device__ inline float dpp_add(float x) {
    int y = __builtin_amdgcn_mov_dpp(__float_as_int(x), CTRL, 0xf, 0xf, true);
    return x + __int_as_float(y);
}
static __device__ inline float row16_sum(float x) {
    x = dpp_add<0x128>(x);   // ror 8
    x = dpp_add<0x124>(x);   // ror 4
    x = dpp_add<0x122>(x);   // ror 2
    x = dpp_add<0x121>(x);   // ror 1
    return x;                // all 16 lanes of the row hold the sum
}

// ---------------- fp32 -> bf16 table pre-pass ----------------
__global__ __launch_bounds__(256)
void cvt_tables(const float* __restrict__ zu, const float* __restrict__ zb,
                __bf16* __restrict__ ubf, __bf16* __restrict__ bbf,
                const int n8u, const int n8b)
{
    int i = blockIdx.x * blockDim.x + threadIdx.x;
    const int stride = gridDim.x * blockDim.x;
    const int tot = n8u + n8b;
    for (; i < tot; i += stride) {
        const float* src; __bf16* dst; int j;
        if (i < n8u) { src = zu; dst = ubf; j = i; }
        else         { src = zb; dst = bbf; j = i - n8u; }
        const float4* p = (const float4*)(src + (size_t)j * 8);
        *(bf16x8*)(dst + (size_t)j * 8) = cvt8(p[0], p[1]);
    }
}

// ---------------- stage buffers (pipeline load destinations) ----------------
template<bool BF> struct Stage;
template<> struct Stage<true>  { bf16x8 a0, a1, a2, a3; };          // 16 VGPR
template<> struct Stage<false> { float4 x0,x1,x2,x3,x4,x5,x6,x7; }; // 32 VGPR

template<bool BF>
static __device__ inline void issue_gather(Stage<BF>& S,
                                           const void* __restrict__ zu,
                                           const void* __restrict__ zb,
                                           int r, int c, int quad) {
    if constexpr (BF) {
        // bf16 row = 128 B; lane(m,q) reads 16 B at q*16 -> A-frag k=q*8+j directly.
        const char* up = (const char*)zu + ((size_t)r << 7) + quad * 16;
        const char* vp = (const char*)zb + ((size_t)c << 7) + quad * 16;
        S.a0 = *(const bf16x8*)(up);        // k in [0,32)
        S.a1 = *(const bf16x8*)(up + 64);   // k in [32,64)
        S.a2 = *(const bf16x8*)(vp);        // k in [64,96)
        S.a3 = *(const bf16x8*)(vp + 64);   // k in [96,128)
    } else {
        const float4* up = (const float4*)((const float*)zu + ((size_t)r << 6));
        const float4* vp = (const float4*)((const float*)zb + ((size_t)c << 6));
        const int q2 = quad * 2;
        S.x0 = up[q2];     S.x1 = up[q2 + 1];
        S.x2 = up[q2 + 8]; S.x3 = up[q2 + 9];
        S.x4 = vp[q2];     S.x5 = vp[q2 + 1];
        S.x6 = vp[q2 + 8]; S.x7 = vp[q2 + 9];
    }
}

template<bool BF>
static __device__ inline void to_frags(const Stage<BF>& S, bf16x8 A[4]) {
    if constexpr (BF) { A[0] = S.a0; A[1] = S.a1; A[2] = S.a2; A[3] = S.a3; }
    else {
        A[0] = cvt8(S.x0, S.x1); A[1] = cvt8(S.x2, S.x3);
        A[2] = cvt8(S.x4, S.x5); A[3] = cvt8(S.x6, S.x7);
    }
}

// MFMA 16x16x32 bf16 layouts (measured, cdna_hip_programming.md §3):
//   A: lane holds A[m=lane&15][k=quad*8+j]
//   B: lane holds B[k=quad*8+j][n=lane&15]
//   C/D: lane reg r holds D[row=quad*4+r][col=lane&15]
template<bool BF, int MINW>
__global__ __launch_bounds__(256, MINW)
void edge_decoder(const void* __restrict__ zu,
                  const void* __restrict__ zb,
                  const int*  __restrict__ eidx,
                  const float* __restrict__ w1,
                  const float* __restrict__ b1,
                  const float* __restrict__ w2,
                  const float* __restrict__ b2,
                  float*      __restrict__ out,
                  const int nedges)
{
    const int lane = threadIdx.x & 63;
    const int m    = lane & 15;
    const int quad = lane >> 4;

    // ---- W1 B-fragments in registers (64 VGPR), fp32 -> bf16 once ----
    bf16x8 Bf[4][4];
#pragma unroll
    for (int t = 0; t < 4; ++t) {
        const float4* wrow = (const float4*)(w1 + (size_t)(t * 16 + m) * 128);
#pragma unroll
        for (int s = 0; s < 4; ++s) {
            const int c0 = s * 8 + quad * 2;
            Bf[t][s] = cvt8(wrow[c0], wrow[c0 + 1]);
        }
    }

    float w2v[4], b1v[4];
#pragma unroll
    for (int t = 0; t < 4; ++t) {
        w2v[t] = w2[t * 16 + m];
        b1v[t] = b1[t * 16 + m];
    }
    const float b2f = b2[0];

    const int* __restrict__ rowp = eidx;
    const int* __restrict__ colp = eidx + nedges;
    const int ngroups = (nedges + 15) >> 4;

    const int wavesPerBlock = blockDim.x >> 6;
    const int gwave = blockIdx.x * wavesPerBlock + (threadIdx.x >> 6);
    const int nw    = gridDim.x * wavesPerBlock;
    const int nw2   = nw << 1;

    // Clamped index load so tail/overrun groups gather a valid row.
    auto load_idx = [&](int gg, int& r, int& c) {
        int e = (gg < ngroups) ? ((gg << 4) + m) : 0;
        if (e >= nedges) e = nedges - 1;
        r = rowp[e]; c = colp[e];
    };

    auto compute_store = [&](const Stage<BF>& S, int gg) {
        bf16x8 A[4];
        to_frags<BF>(S, A);

        f32x4 acc[4];
#pragma unroll
        for (int t = 0; t < 4; ++t)
            acc[t] = (f32x4){b1v[t], b1v[t], b1v[t], b1v[t]};   // b1 folded into init

#pragma unroll
        for (int s = 0; s < 4; ++s)
#pragma unroll
            for (int t = 0; t < 4; ++t)
                acc[t] = __builtin_amdgcn_mfma_f32_16x16x32_bf16(A[s], Bf[t][s], acc[t], 0, 0, 0);

        // Epilogue: h=relu(acc); lane-partial dot with W2; VALU/DPP reduce
        // over the 16 n-lanes of each quad (LDS pipe untouched).
        float p[4] = {0.f, 0.f, 0.f, 0.f};
#pragma unroll
        for (int t = 0; t < 4; ++t)
#pragma unroll
            for (int rr = 0; rr < 4; ++rr)
                p[rr] = fmaf(fmaxf(acc[t][rr], 0.f), w2v[t], p[rr]);

#pragma unroll
        for (int rr = 0; rr < 4; ++rr)
            p[rr] = row16_sum(p[rr]);

        if (m == 0) {
            const int eo = (gg << 4) + quad * 4;   // >= nedges for overrun groups
            if (eo + 3 < nedges) {
                float4 o;
                o.x = p[0] + b2f; o.y = p[1] + b2f;
                o.z = p[2] + b2f; o.w = p[3] + b2f;
                *(float4*)(out + eo) = o;
            } else {
#pragma unroll
                for (int rr = 0; rr < 4; ++rr)
                    if (eo + rr < nedges) out[eo + rr] = p[rr] + b2f;
            }
        }
    };

    // ---- 2-deep software pipeline: compute(S0) overlaps S1's in-flight loads ----
    int g = gwave;
    int r0, c0, r1, c1;
    Stage<BF> S0, S1;

    load_idx(g,      r0, c0);
    load_idx(g + nw, r1, c1);
    issue_gather<BF>(S0, zu, zb, r0, c0, quad);
    issue_gather<BF>(S1, zu, zb, r1, c1, quad);
    load_idx(g + nw2,      r0, c0);
    load_idx(g + nw2 + nw, r1, c1);

    for (; g < ngroups; g += nw2) {
        compute_store(S0, g);
        issue_gather<BF>(S0, zu, zb, r0, c0, quad);      // group g+2nw
        load_idx(g + nw2 + nw2, r0, c0);                 // group g+4nw pending

        compute_store(S1, g + nw);
        issue_gather<BF>(S1, zu, zb, r1, c1, quad);      // group g+3nw
        load_idx(g + nw2 + nw2 + nw, r1, c1);            // group g+5nw pending
    }
}

extern "C" void kernel_launch(void* const* d_in, const int* in_sizes, int n_in,
                              void* d_out, int out_size, void* d_ws, size_t ws_size,
                              hipStream_t stream) {
    const float* zu = (const float*)d_in[0];
    const float* zb = (const float*)d_in[1];
    const int*   ei = (const int*)d_in[2];
    const float* w1 = (const float*)d_in[3];
    const float* b1 = (const float*)d_in[4];
    const float* w2 = (const float*)d_in[5];
    const float* b2 = (const float*)d_in[6];
    float* out = (float*)d_out;

    const int nedges = in_sizes[2] / 2;        // edge_label_index is [2, E]
    const size_t nzu = (size_t)in_sizes[0];    // z_user elements
    const size_t nzb = (size_t)in_sizes[1];    // z_books elements
    const size_t need = (nzu + nzb) * sizeof(__bf16);

    dim3 grid(2048), block(256);

    if (d_ws != nullptr && ws_size >= need) {
        // Pre-pass: bf16 copies of the tables in workspace (~13 us), then the
        // main kernel gathers HALF the bytes and loads A-fragments directly.
        __bf16* ubf = (__bf16*)d_ws;
        __bf16* bbf = ubf + nzu;
        hipLaunchKernelGGL(cvt_tables, dim3(1024), block, 0, stream,
                           zu, zb, ubf, bbf, (int)(nzu / 8), (int)(nzb / 8));
        hipLaunchKernelGGL((edge_decoder<true, 3>), grid, block, 0, stream,
                           (const void*)ubf, (const void*)bbf, ei, w1, b1, w2, b2,
                           out, nedges);
    } else {
        // Fallback: gather fp32 rows and convert in-register.
        hipLaunchKernelGGL((edge_decoder<false, 2>), grid, block, 0, stream,
                           (const void*)zu, (const void*)zb, ei, w1, b1, w2, b2,
                           out, nedges);
    }
}

// Round 3
// 188.372 us; speedup vs baseline: 1.2820x; 1.0365x over previous
//
#include <hip/hip_runtime.h>
#include <hip/hip_bf16.h>
#include <hip/hip_fp16.h>
#include <stdint.h>

typedef __bf16    bf16x8  __attribute__((ext_vector_type(8)));
typedef float     f32x4   __attribute__((ext_vector_type(4)));
typedef _Float16  half2_t __attribute__((ext_vector_type(2)));
typedef _Float16  half8_t __attribute__((ext_vector_type(8)));

// Convert 8 consecutive fp32 (two float4s) to a bf16x8 fragment (RNE).
static __device__ inline bf16x8 cvt8(const float4 a, const float4 b) {
    bf16x8 r;
    r[0] = (__bf16)a.x; r[1] = (__bf16)a.y; r[2] = (__bf16)a.z; r[3] = (__bf16)a.w;
    r[4] = (__bf16)b.x; r[5] = (__bf16)b.y; r[6] = (__bf16)b.z; r[7] = (__bf16)b.w;
    return r;
}

// ============================================================================
// Pre-pass: h-space tables in f16.
//   U[i][n] = sum_k zu[i][k]*W1[n][k]     (k in [0,64))  + b1[n]
//   B[j][n] = sum_k zb[j][k]*W1[n][64+k]  (k in [0,64))
// MFMA 16x16x32 bf16; D layout: lane reg r -> D[row=quad*4+r][col=lane&15].
// Per-wave LDS transpose (no barrier needed: wave-private slab) then f16 store.
// ============================================================================
__global__ __launch_bounds__(256, 2)
void build_h_tables(const float* __restrict__ zu, const float* __restrict__ zb,
                    const float* __restrict__ w1, const float* __restrict__ b1,
                    _Float16* __restrict__ U, _Float16* __restrict__ B,
                    const int nu, const int nb)
{
    __shared__ float lds[4 * 16 * 68];          // 4 waves x (16 rows x 68 f32)
    const int wid  = threadIdx.x >> 6;
    const int lane = threadIdx.x & 63;
    const int m    = lane & 15;
    const int quad = lane >> 4;

    const int gu = (nu + 15) >> 4;
    const int gb = (nb + 15) >> 4;
    const int wg = blockIdx.x * 4 + wid;
    if (wg >= gu + gb) return;

    const int sel      = (wg >= gu);
    const int g        = sel ? (wg - gu) : wg;
    const int nrows    = sel ? nb : nu;
    const float* zsrc  = sel ? zb : zu;
    _Float16*    dst   = sel ? B  : U;
    const int koffc    = sel ? 16 : 0;          // W1 float4-chunk offset (64 floats)

    // B-fragments: Bf[t][s] = bf16(W1[n=t*16+m][koff + s*32 + quad*8 + j])
    bf16x8 Bf[4][2];
#pragma unroll
    for (int t = 0; t < 4; ++t) {
        const float4* wrow = (const float4*)(w1 + (size_t)(t * 16 + m) * 128);
#pragma unroll
        for (int s = 0; s < 2; ++s) {
            const int c0 = koffc + s * 8 + quad * 2;
            Bf[t][s] = cvt8(wrow[c0], wrow[c0 + 1]);
        }
    }

    // A-fragments: z row g*16+m (clamped), k = s*32 + quad*8 + j
    int rowz = g * 16 + m;
    if (rowz >= nrows) rowz = nrows - 1;
    const float4* zr = (const float4*)(zsrc + (size_t)rowz * 64);
    const bf16x8 A0 = cvt8(zr[quad * 2],     zr[quad * 2 + 1]);
    const bf16x8 A1 = cvt8(zr[8 + quad * 2], zr[9 + quad * 2]);

    f32x4 acc[4];
#pragma unroll
    for (int t = 0; t < 4; ++t) {
        const float bv = sel ? 0.f : b1[t * 16 + m];   // b1 folded into U only
        acc[t] = (f32x4){bv, bv, bv, bv};
    }
#pragma unroll
    for (int t = 0; t < 4; ++t) {
        acc[t] = __builtin_amdgcn_mfma_f32_16x16x32_bf16(A0, Bf[t][0], acc[t], 0, 0, 0);
        acc[t] = __builtin_amdgcn_mfma_f32_16x16x32_bf16(A1, Bf[t][1], acc[t], 0, 0, 0);
    }

    // Transpose through the wave-private LDS slab (stride 68 f32: 16B-aligned
    // rows, bank-rotating) so stores are row-contiguous.
    float* slab = lds + wid * (16 * 68);
#pragma unroll
    for (int t = 0; t < 4; ++t)
#pragma unroll
        for (int r = 0; r < 4; ++r)
            slab[(quad * 4 + r) * 68 + t * 16 + m] = acc[t][r];

    // Read back row m, cols [quad*16, quad*16+16)  (compiler inserts lgkmcnt).
    const float4* rd = (const float4*)(slab + m * 68 + quad * 16);
    const float4 f0 = rd[0], f1 = rd[1], f2 = rd[2], f3 = rd[3];

    half8_t h0, h1;
    h0[0] = (_Float16)f0.x; h0[1] = (_Float16)f0.y; h0[2] = (_Float16)f0.z; h0[3] = (_Float16)f0.w;
    h0[4] = (_Float16)f1.x; h0[5] = (_Float16)f1.y; h0[6] = (_Float16)f1.z; h0[7] = (_Float16)f1.w;
    h1[0] = (_Float16)f2.x; h1[1] = (_Float16)f2.y; h1[2] = (_Float16)f2.z; h1[3] = (_Float16)f2.w;
    h1[4] = (_Float16)f3.x; h1[5] = (_Float16)f3.y; h1[6] = (_Float16)f3.z; h1[7] = (_Float16)f3.w;

    const int orow = g * 16 + m;
    if (orow < nrows) {
        half8_t* o = (half8_t*)(dst + (size_t)orow * 64 + quad * 16);
        o[0] = h0;
        o[1] = h1;
    }
}

// ============================================================================
// Main kernel: out[e] = dot(relu(U[r] + B[c]), w2) + b2  -- pure gather+VALU.
// 16 edges/wave-group; lane(m,quad): edge m, h-dims [quad*16, quad*16+16).
// 4-deep software pipeline (16 VGPR/stage), indices prefetched 8 groups ahead.
// ============================================================================
struct StageH { half8_t u0, u1, v0, v1; };      // 16 VGPR

__global__ __launch_bounds__(256, 4)
void edge_decoder_h(const _Float16* __restrict__ U, const _Float16* __restrict__ B,
                    const int*   __restrict__ eidx,
                    const float* __restrict__ w2, const float* __restrict__ b2,
                    float*       __restrict__ out, const int nedges)
{
    const int lane = threadIdx.x & 63;
    const int m    = lane & 15;
    const int quad = lane >> 4;

    // w2 as f16 pairs for v_dot2_f32_f16: w2h[i] covers dims quad*16 + {2i,2i+1}.
    half2_t w2h[8];
#pragma unroll
    for (int i = 0; i < 8; ++i) {
        w2h[i][0] = (_Float16)w2[quad * 16 + 2 * i];
        w2h[i][1] = (_Float16)w2[quad * 16 + 2 * i + 1];
    }
    const float b2f = b2[0];

    const int* __restrict__ rowp = eidx;
    const int* __restrict__ colp = eidx + nedges;
    const int ngroups = (nedges + 15) >> 4;

    const int wavesPerBlock = blockDim.x >> 6;
    const int gwave = blockIdx.x * wavesPerBlock + (threadIdx.x >> 6);
    const int nw    = gridDim.x * wavesPerBlock;

    int r[4], c[4];
    StageH S[4];

    auto load_idx = [&](int gg, int k) {
        int e = (gg < ngroups) ? ((gg << 4) + m) : 0;
        if (e >= nedges) e = nedges - 1;
        r[k] = rowp[e];
        c[k] = colp[e];
    };
    auto gath = [&](int k) {
        const char* up = (const char*)U + ((size_t)r[k] << 7) + quad * 32;
        const char* vp = (const char*)B + ((size_t)c[k] << 7) + quad * 32;
        S[k].u0 = *(const half8_t*)(up);
        S[k].u1 = *(const half8_t*)(up + 16);
        S[k].v0 = *(const half8_t*)(vp);
        S[k].v1 = *(const half8_t*)(vp + 16);
    };
    auto comp = [&](int k, int gg) {
        float p = 0.f;
        const half2_t zero = {(_Float16)0, (_Float16)0};
#pragma unroll
        for (int i = 0; i < 4; ++i) {
            half2_t a, b;
            a[0] = S[k].u0[2 * i]; a[1] = S[k].u0[2 * i + 1];
            b[0] = S[k].v0[2 * i]; b[1] = S[k].v0[2 * i + 1];
            half2_t h = __builtin_elementwise_max(a + b, zero);   // v_pk_add + v_pk_max
#if __has_builtin(__builtin_amdgcn_fdot2)
            p = __builtin_amdgcn_fdot2(h, w2h[i], p, false);      // v_dot2_f32_f16
#else
            p = fmaf((float)h[0], (float)w2h[i][0], p);
            p = fmaf((float)h[1], (float)w2h[i][1], p);
#endif
        }
#pragma unroll
        for (int i = 0; i < 4; ++i) {
            half2_t a, b;
            a[0] = S[k].u1[2 * i]; a[1] = S[k].u1[2 * i + 1];
            b[0] = S[k].v1[2 * i]; b[1] = S[k].v1[2 * i + 1];
            half2_t h = __builtin_elementwise_max(a + b, zero);
#if __has_builtin(__builtin_amdgcn_fdot2)
            p = __builtin_amdgcn_fdot2(h, w2h[4 + i], p, false);
#else
            p = fmaf((float)h[0], (float)w2h[4 + i][0], p);
            p = fmaf((float)h[1], (float)w2h[4 + i][1], p);
#endif
        }
        // Reduce the 4 quad-partials of edge (gg*16 + m).
        p += __shfl_xor(p, 16, 64);
        p += __shfl_xor(p, 32, 64);
        if (quad == 0) {
            const int e = (gg << 4) + m;
            if (e < nedges) out[e] = p + b2f;      // 16-lane coalesced 64B store
        }
    };

    // Prologue: fill all 4 stages, then prefetch the next 4 groups' indices.
#pragma unroll
    for (int k = 0; k < 4; ++k) load_idx(gwave + k * nw, k);
#pragma unroll
    for (int k = 0; k < 4; ++k) gath(k);
#pragma unroll
    for (int k = 0; k < 4; ++k) load_idx(gwave + (k + 4) * nw, k);

    for (int g = gwave; g < ngroups; g += 4 * nw) {
#pragma unroll
        for (int k = 0; k < 4; ++k) {
            comp(k, g + k * nw);                   // consume stage k
            gath(k);                               // refill: group g+(k+4)*nw
            load_idx(g + (k + 8) * nw, k);         // prefetch idx 8 groups ahead
        }
    }
}

// ============================================================================
// Fallback (workspace missing): round-2 fp32-gather MFMA kernel.
// ============================================================================
template<int CTRL>
static __device__ inline float dpp_add(float x) {
    int y = __builtin_amdgcn_mov_dpp(__float_as_int(x), CTRL, 0xf, 0xf, true);
    return x + __int_as_float(y);
}
static __device__ inline float row16_sum(float x) {
    x = dpp_add<0x128>(x); x = dpp_add<0x124>(x);
    x = dpp_add<0x122>(x); x = dpp_add<0x121>(x);
    return x;
}

__global__ __launch_bounds__(256, 2)
void edge_decoder_f32(const float* __restrict__ zu, const float* __restrict__ zb,
                      const int*   __restrict__ eidx,
                      const float* __restrict__ w1, const float* __restrict__ b1,
                      const float* __restrict__ w2, const float* __restrict__ b2,
                      float*       __restrict__ out, const int nedges)
{
    const int lane = threadIdx.x & 63;
    const int m    = lane & 15;
    const int quad = lane >> 4;

    bf16x8 Bf[4][4];
#pragma unroll
    for (int t = 0; t < 4; ++t) {
        const float4* wrow = (const float4*)(w1 + (size_t)(t * 16 + m) * 128);
#pragma unroll
        for (int s = 0; s < 4; ++s) {
            const int c0 = s * 8 + quad * 2;
            Bf[t][s] = cvt8(wrow[c0], wrow[c0 + 1]);
        }
    }
    float w2v[4], b1v[4];
#pragma unroll
    for (int t = 0; t < 4; ++t) { w2v[t] = w2[t * 16 + m]; b1v[t] = b1[t * 16 + m]; }
    const float b2f = b2[0];

    const int* __restrict__ rowp = eidx;
    const int* __restrict__ colp = eidx + nedges;
    const int ngroups = (nedges + 15) >> 4;
    const int gwave = blockIdx.x * (blockDim.x >> 6) + (threadIdx.x >> 6);
    const int nw    = gridDim.x * (blockDim.x >> 6);

    for (int g = gwave; g < ngroups; g += nw) {
        int e = (g << 4) + m;
        if (e >= nedges) e = nedges - 1;
        const int rr0 = rowp[e], cc0 = colp[e];
        const float4* up = (const float4*)(zu + ((size_t)rr0 << 6));
        const float4* vp = (const float4*)(zb + ((size_t)cc0 << 6));
        const int q2 = quad * 2;
        bf16x8 A[4];
        A[0] = cvt8(up[q2], up[q2 + 1]);  A[1] = cvt8(up[q2 + 8], up[q2 + 9]);
        A[2] = cvt8(vp[q2], vp[q2 + 1]);  A[3] = cvt8(vp[q2 + 8], vp[q2 + 9]);

        f32x4 acc[4];
#pragma unroll
        for (int t = 0; t < 4; ++t) acc[t] = (f32x4){b1v[t], b1v[t], b1v[t], b1v[t]};
#pragma unroll
        for (int s = 0; s < 4; ++s)
#pragma unroll
            for (int t = 0; t < 4; ++t)
                acc[t] = __builtin_amdgcn_mfma_f32_16x16x32_bf16(A[s], Bf[t][s], acc[t], 0, 0, 0);

        float p[4] = {0.f, 0.f, 0.f, 0.f};
#pragma unroll
        for (int t = 0; t < 4; ++t)
#pragma unroll
            for (int rr = 0; rr < 4; ++rr)
                p[rr] = fmaf(fmaxf(acc[t][rr], 0.f), w2v[t], p[rr]);
#pragma unroll
        for (int rr = 0; rr < 4; ++rr) p[rr] = row16_sum(p[rr]);

        if (m == 0) {
            const int eo = (g << 4) + quad * 4;
            if (eo + 3 < nedges) {
                float4 o; o.x = p[0] + b2f; o.y = p[1] + b2f; o.z = p[2] + b2f; o.w = p[3] + b2f;
                *(float4*)(out + eo) = o;
            } else {
#pragma unroll
                for (int rr = 0; rr < 4; ++rr)
                    if (eo + rr < nedges) out[eo + rr] = p[rr] + b2f;
            }
        }
    }
}

extern "C" void kernel_launch(void* const* d_in, const int* in_sizes, int n_in,
                              void* d_out, int out_size, void* d_ws, size_t ws_size,
                              hipStream_t stream) {
    const float* zu = (const float*)d_in[0];
    const float* zb = (const float*)d_in[1];
    const int*   ei = (const int*)d_in[2];
    const float* w1 = (const float*)d_in[3];
    const float* b1 = (const float*)d_in[4];
    const float* w2 = (const float*)d_in[5];
    const float* b2 = (const float*)d_in[6];
    float* out = (float*)d_out;

    const int nedges = in_sizes[2] / 2;        // edge_label_index is [2, E] int32
    const int nu = in_sizes[0] / 64;           // z_user rows
    const int nb = in_sizes[1] / 64;           // z_books rows
    const size_t need = ((size_t)nu + nb) * 64 * sizeof(_Float16);

    if (d_ws != nullptr && ws_size >= need) {
        _Float16* U = (_Float16*)d_ws;
        _Float16* B = U + (size_t)nu * 64;

        const int total_wg = ((nu + 15) >> 4) + ((nb + 15) >> 4);
        dim3 pgrid((total_wg + 3) / 4), block(256);
        hipLaunchKernelGGL(build_h_tables, pgrid, block, 0, stream,
                           zu, zb, w1, b1, U, B, nu, nb);

        dim3 grid(2048);
        hipLaunchKernelGGL(edge_decoder_h, grid, block, 0, stream,
                           U, B, ei, w2, b2, out, nedges);
    } else {
        dim3 grid(2048), block(256);
        hipLaunchKernelGGL(edge_decoder_f32, grid, block, 0, stream,
                           zu, zb, ei, w1, b1, w2, b2, out, nedges);
    }
}